// Round 8
// baseline (237.159 us; speedup 1.0000x reference)
//
#include <hip/hip_runtime.h>
#include <hip/hip_bf16.h>

#define EMBED 384
#define SEQ   1024
#define NBATCH 16
#define NH    6
#define HD    64

typedef __bf16 bf16;
typedef bf16  bf16x8 __attribute__((ext_vector_type(8)));
typedef bf16  bf16x4 __attribute__((ext_vector_type(4)));
typedef float f32x4  __attribute__((ext_vector_type(4)));

#define MFMA16(a, b, c) __builtin_amdgcn_mfma_f32_16x16x32_bf16((a), (b), (c), 0, 0, 0)

// q is pre-scaled by this in k_qkv so attention is P = exp2(S) directly
#define QSCALE 0.18033688011112042f  // 0.125 * log2(e)

// async global->LDS, 16B per lane; LDS dst = wave-uniform base + lane*16
__device__ __forceinline__ void gload_lds16(const void* g, void* l) {
    __builtin_amdgcn_global_load_lds(
        (const __attribute__((address_space(1))) void*)g,
        (__attribute__((address_space(3))) void*)l, 16, 0, 0);
}

// ---------------------------------------------------------------------------
// K-1: f32 -> bf16 conversion for both weight arrays, float4-vectorized
// ---------------------------------------------------------------------------
__global__ __launch_bounds__(256) void k_cvt2(const float* __restrict__ a,
                                              const float* __restrict__ b,
                                              bf16* __restrict__ da,
                                              bf16* __restrict__ db,
                                              int na, int nb) {
    int i = (blockIdx.x * 256 + threadIdx.x) * 4;
    if (i < na) {
        float4 v = *reinterpret_cast<const float4*>(a + i);
        bf16x4 o = {(bf16)v.x, (bf16)v.y, (bf16)v.z, (bf16)v.w};
        *reinterpret_cast<bf16x4*>(da + i) = o;
    } else {
        int j = i - na;
        if (j < nb) {
            float4 v = *reinterpret_cast<const float4*>(b + j);
            bf16x4 o = {(bf16)v.x, (bf16)v.y, (bf16)v.z, (bf16)v.w};
            *reinterpret_cast<bf16x4*>(db + j) = o;
        }
    }
}

// ---------------------------------------------------------------------------
// K0: x[n][c][s] (f32) -> tok[n][s][c] (bf16)  tile transpose through LDS
// ---------------------------------------------------------------------------
__global__ __launch_bounds__(256) void k_transpose(const float* __restrict__ x,
                                                   bf16* __restrict__ tok) {
    __shared__ bf16 tile[64][66];
    int n  = blockIdx.z;
    int s0 = blockIdx.x * 64;
    int c0 = blockIdx.y * 64;
    int tid = threadIdx.x;

    int sl  = tid & 63;
    int cl0 = tid >> 6;  // 0..3
#pragma unroll
    for (int i = 0; i < 16; ++i) {
        int cl = cl0 + i * 4;
        tile[cl][sl] = (bf16)x[((size_t)n * EMBED + (c0 + cl)) * SEQ + s0 + sl];
    }
    __syncthreads();
    int cl  = tid & 63;
    int sl0 = tid >> 6;
#pragma unroll
    for (int i = 0; i < 16; ++i) {
        int s = sl0 + i * 4;
        tok[((size_t)n * SEQ + (s0 + s)) * EMBED + c0 + cl] = tile[cl][s];
    }
}

// ---------------------------------------------------------------------------
// K1: qkv, double-buffered LDS staging (BK=32), strength-reduced + unrolled.
//   q is written pre-scaled by QSCALE (folds softmax scale out of k_attn).
// ---------------------------------------------------------------------------
__global__ __launch_bounds__(256) void k_qkv(const bf16* __restrict__ tok,
                                             const bf16* __restrict__ wqkv,
                                             bf16* __restrict__ qout,
                                             bf16* __restrict__ kout,
                                             bf16* __restrict__ vtout) {
    __shared__ __align__(16) bf16 At[2][128 * 32];  // 8KB each, 64B rows
    __shared__ __align__(16) bf16 Bt[2][128 * 32];

    int b    = blockIdx.x;       // 1152 blocks
    int bm   = b & 7;            // 8 s-tiles -> XCD
    int g    = b >> 3;
    int bn   = g % 9;            // 9 o-tiles
    int n    = g / 9;
    int wave = threadIdx.x >> 6;
    int lane = threadIdx.x & 63;
    int row16 = lane & 15;
    int quad  = lane >> 4;
    int sw_base = (wave >> 1) * 64;   // wave row offset within tile
    int ow_base = (wave & 1) * 64;

    const bf16* Ag = tok  + ((size_t)n * SEQ + bm * 128) * EMBED;
    const bf16* Bg = wqkv + (size_t)bn * 128 * EMBED;

    // hoisted per-lane staging sources; per-step advance = +32 elems
    int srow = lane >> 2;        // 0..15 within 16-row slab
    int scol = (lane & 3) * 8;   // 8 elems = 16B
    const bf16* Abase = Ag + (size_t)(wave * 32 + srow) * EMBED + scol;
    const bf16* Bbase = Bg + (size_t)(wave * 32 + srow) * EMBED + scol;
    bf16* AtW = &At[0][0] + wave * 32 * 32;   // uniform LDS slab base (wave rows)
    bf16* BtW = &Bt[0][0] + wave * 32 * 32;

    auto stage = [&](int kk, int bi) {
        gload_lds16(Abase + kk,               AtW + bi * 128 * 32);
        gload_lds16(Abase + kk + 16 * EMBED,  AtW + bi * 128 * 32 + 16 * 32);
        gload_lds16(Bbase + kk,               BtW + bi * 128 * 32);
        gload_lds16(Bbase + kk + 16 * EMBED,  BtW + bi * 128 * 32 + 16 * 32);
    };

    stage(0, 0);

    f32x4 acc[4][4] = {};
#pragma unroll
    for (int step = 0; step < 12; ++step) {
        __syncthreads();                       // drain staging, publish LDS
        int cur = step & 1;
        if (step + 1 < 12) stage((step + 1) * 32, cur ^ 1);

        bf16x8 af[4], bfr[4];
#pragma unroll
        for (int mt = 0; mt < 4; ++mt)
            af[mt] = *reinterpret_cast<const bf16x8*>(
                &At[cur][(sw_base + mt * 16 + row16) * 32 + quad * 8]);
#pragma unroll
        for (int nt = 0; nt < 4; ++nt)
            bfr[nt] = *reinterpret_cast<const bf16x8*>(
                &Bt[cur][(ow_base + nt * 16 + row16) * 32 + quad * 8]);
#pragma unroll
        for (int mt = 0; mt < 4; ++mt)
#pragma unroll
            for (int nt = 0; nt < 4; ++nt)
                acc[mt][nt] = MFMA16(af[mt], bfr[nt], acc[mt][nt]);
    }

    int s_base = bm * 128 + sw_base;
    int o_base = bn * 128 + ow_base;
    int part = (bn * 128) / EMBED;  // o-tile never crosses a part boundary
#pragma unroll
    for (int mt = 0; mt < 4; ++mt)
#pragma unroll
        for (int nt = 0; nt < 4; ++nt) {
            int o   = o_base + nt * 16 + row16;
            int rem = o - part * EMBED;
            int h = rem >> 6;
            int d = rem & 63;
            if (part == 0) {        // q: pre-scale by 0.125*log2(e)
#pragma unroll
                for (int r = 0; r < 4; ++r) {
                    int s = s_base + mt * 16 + quad * 4 + r;
                    qout[(((size_t)n * NH + h) * SEQ + s) * HD + d] =
                        (bf16)(acc[mt][nt][r] * QSCALE);
                }
            } else if (part == 1) { // k
#pragma unroll
                for (int r = 0; r < 4; ++r) {
                    int s = s_base + mt * 16 + quad * 4 + r;
                    kout[(((size_t)n * NH + h) * SEQ + s) * HD + d] = (bf16)acc[mt][nt][r];
                }
            } else {                // vT: 4 consecutive s -> 8B store
                int s = s_base + mt * 16 + quad * 4;
                bf16x4 pack;
#pragma unroll
                for (int r = 0; r < 4; ++r) pack[r] = (bf16)acc[mt][nt][r];
                *reinterpret_cast<bf16x4*>(
                    &vtout[(((size_t)n * NH + h) * HD + d) * SEQ + s]) = pack;
            }
        }
}

// ---------------------------------------------------------------------------
// K2: attention v5 = v4 (XOR-swizzled LDS, XCD-local heads) + strength-reduced
//   staging addresses + fully unrolled t-loop + P = exp2(S) (scale folded
//   into q by k_qkv).
// ---------------------------------------------------------------------------
__global__ __launch_bounds__(256) void k_attn(const bf16* __restrict__ q,
                                              const bf16* __restrict__ kmat,
                                              const bf16* __restrict__ vT,
                                              bf16* __restrict__ ao) {
    __shared__ __align__(16) bf16 ktile[2][64 * 64];   // swizzled [t][d]
    __shared__ __align__(16) bf16 vtile[2][64 * 64];   // swizzled [d][t]
    __shared__ __align__(16) bf16 pshare[4][16][72];   // wave-private P tile

    int b     = blockIdx.x;      // 1536 blocks
    int lane8 = b & 7;           // -> XCD (round-robin heuristic)
    int g     = b >> 3;
    int nh    = (g % 12) * 8 + lane8;   // all qt of one nh share lane8
    int qt    = g / 12;
    int n = nh / NH, h = nh % NH;

    int wave = threadIdx.x >> 6;
    int lane = threadIdx.x & 63;
    int row16 = lane & 15;
    int quad  = lane >> 4;
    int sw    = row16 & 7;       // read-side swizzle key
    int s_row = qt * 64 + wave * 16;

    const bf16* qh = q    + ((size_t)n * NH + h) * SEQ * HD;
    const bf16* kh = kmat + ((size_t)n * NH + h) * SEQ * HD;
    const bf16* vh = vT   + ((size_t)n * NH + h) * HD * SEQ;

    bf16x8 qf0 = *reinterpret_cast<const bf16x8*>(qh + (size_t)(s_row + row16) * HD + quad * 8);
    bf16x8 qf1 = *reinterpret_cast<const bf16x8*>(qh + (size_t)(s_row + row16) * HD + 32 + quad * 8);

    // hoisted per-lane staging sources. Slab j=+8 keeps (row&7) -> same ck.
    int r0   = wave * 16;
    int srow = r0 + (lane >> 3);           // tile row this lane feeds (j=0 slab)
    int ck   = (lane & 7) ^ (srow & 7);    // swizzled source chunk (j-invariant)
    const bf16* kbase = kh + (size_t)srow * HD + ck * 8;   // +t0*HD per iter
    const bf16* vbase = vh + (size_t)srow * SEQ + ck * 8;  // +t0 per iter
    bf16* ktW = &ktile[0][0] + r0 * 64;    // uniform LDS slab bases
    bf16* vtW = &vtile[0][0] + r0 * 64;

    auto stage = [&](int t0, int bi) {
        int lb = bi * 64 * 64;
        gload_lds16(kbase + (size_t)t0 * HD,           ktW + lb);
        gload_lds16(kbase + (size_t)t0 * HD + 8 * HD,  ktW + lb + 8 * 64);
        gload_lds16(vbase + t0,                        vtW + lb);
        gload_lds16(vbase + t0 + 8 * SEQ,              vtW + lb + 8 * 64);
    };

    stage(0, 0);

    float lsum[4] = {0.f, 0.f, 0.f, 0.f};
    f32x4 oacc[4] = {};

#pragma unroll
    for (int it = 0; it < 16; ++it) {
        __syncthreads();                 // drains own staging loads + publishes LDS
        int cur = it & 1;
        if (it + 1 < 16) stage((it + 1) * 64, cur ^ 1);  // prefetch next tile

        const bf16* kb = &ktile[cur][0];
        const bf16* vb = &vtile[cur][0];

        // S^T = K*Q'^T: lane holds S[m=row16][t=nt*16+quad*4+r]
        f32x4 sacc[4] = {};
#pragma unroll
        for (int nt = 0; nt < 4; ++nt) {
            bf16x8 kf0 = *reinterpret_cast<const bf16x8*>(
                kb + (nt * 16 + row16) * 64 + ((quad ^ sw) * 8));
            bf16x8 kf1 = *reinterpret_cast<const bf16x8*>(
                kb + (nt * 16 + row16) * 64 + (((4 + quad) ^ sw) * 8));
            sacc[nt] = MFMA16(kf0, qf0, sacc[nt]);
            sacc[nt] = MFMA16(kf1, qf1, sacc[nt]);
        }
        // P = exp2(S) (scale pre-folded into q); packed 8B LDS writes
#pragma unroll
        for (int nt = 0; nt < 4; ++nt) {
            bf16x4 pk;
            float ps = 0.f;
#pragma unroll
            for (int r = 0; r < 4; ++r) {
                float e = __builtin_amdgcn_exp2f(sacc[nt][r]);
                ps += e;
                pk[r] = (bf16)e;
            }
            lsum[nt] += ps;
            *reinterpret_cast<bf16x4*>(&pshare[wave][row16][nt * 16 + quad * 4]) = pk;
        }
        __builtin_amdgcn_wave_barrier();  // wave-private LDS write -> read order
        bf16x8 pf0 = *reinterpret_cast<const bf16x8*>(&pshare[wave][row16][quad * 8]);
        bf16x8 pf1 = *reinterpret_cast<const bf16x8*>(&pshare[wave][row16][32 + quad * 8]);
        __builtin_amdgcn_wave_barrier();  // read -> next iter's writes
        // O += P*V
#pragma unroll
        for (int dt = 0; dt < 4; ++dt) {
            bf16x8 vf0 = *reinterpret_cast<const bf16x8*>(
                vb + (dt * 16 + row16) * 64 + ((quad ^ sw) * 8));
            bf16x8 vf1 = *reinterpret_cast<const bf16x8*>(
                vb + (dt * 16 + row16) * 64 + (((4 + quad) ^ sw) * 8));
            oacc[dt] = MFMA16(pf0, vf0, oacc[dt]);
            oacc[dt] = MFMA16(pf1, vf1, oacc[dt]);
        }
    }

    // row-sum: lane's lsum covers t ≡ {4*quad..4*quad+3} mod 16 for row=row16
    float tot = (lsum[0] + lsum[1]) + (lsum[2] + lsum[3]);
    tot += __shfl_xor(tot, 16, 64);
    tot += __shfl_xor(tot, 32, 64);
    float inv = 1.0f / tot;  // valid for row = lane&15

    float linv[4];
#pragma unroll
    for (int r = 0; r < 4; ++r) linv[r] = __shfl(inv, quad * 4 + r, 64);

#pragma unroll
    for (int dt = 0; dt < 4; ++dt)
#pragma unroll
        for (int r = 0; r < 4; ++r) {
            int s = s_row + quad * 4 + r;
            int d = dt * 16 + row16;
            ao[((size_t)n * SEQ + s) * EMBED + h * HD + d] = (bf16)(oacc[dt][r] * linv[r]);
        }
}

// ---------------------------------------------------------------------------
// K3: out[n][o][s] = bias[o] + sum_c ao[n][s][c] * wout[o][c]   (f32 output)
//   64(s) x 128(o) block tile -> 768 blocks (3/CU), wave tile 32x64.
// ---------------------------------------------------------------------------
__global__ __launch_bounds__(256) void k_proj(const bf16* __restrict__ ao,
                                              const bf16* __restrict__ wout,
                                              const float* __restrict__ bout,
                                              float* __restrict__ out) {
    int b    = blockIdx.x;       // 768 blocks
    int bm   = b & 15;           // 16 s-tiles of 64
    int g    = b >> 4;
    int bn   = g % 3;            // 3 o-tiles
    int n    = g / 3;
    int wave = threadIdx.x >> 6;
    int lane = threadIdx.x & 63;
    int row16 = lane & 15;
    int quad  = lane >> 4;
    int s_base = bm * 64 + (wave >> 1) * 32;
    int o_base = bn * 128 + (wave & 1) * 64;

    const bf16* A = ao + (size_t)n * SEQ * EMBED;

    f32x4 acc[2][4] = {};
    for (int kk = 0; kk < EMBED; kk += 32) {
        bf16x8 af[2], bfr[4];
#pragma unroll
        for (int mt = 0; mt < 2; ++mt)
            af[mt] = *reinterpret_cast<const bf16x8*>(
                A + (size_t)(s_base + mt * 16 + row16) * EMBED + kk + quad * 8);
#pragma unroll
        for (int nt = 0; nt < 4; ++nt)
            bfr[nt] = *reinterpret_cast<const bf16x8*>(
                wout + (size_t)(o_base + nt * 16 + row16) * EMBED + kk + quad * 8);
#pragma unroll
        for (int mt = 0; mt < 2; ++mt)
#pragma unroll
            for (int nt = 0; nt < 4; ++nt)
                acc[mt][nt] = MFMA16(af[mt], bfr[nt], acc[mt][nt]);
    }

#pragma unroll
    for (int nt = 0; nt < 4; ++nt) {
        int o = o_base + nt * 16 + row16;
        float bias = bout[o];
#pragma unroll
        for (int mt = 0; mt < 2; ++mt) {
            int s = s_base + mt * 16 + quad * 4;  // 4 consecutive s, 16B store
            f32x4 pack;
#pragma unroll
            for (int r = 0; r < 4; ++r) pack[r] = acc[mt][nt][r] + bias;
            *reinterpret_cast<f32x4*>(out + ((size_t)n * EMBED + o) * SEQ + s) = pack;
        }
    }
}

// ---------------------------------------------------------------------------
extern "C" void kernel_launch(void* const* d_in, const int* in_sizes, int n_in,
                              void* d_out, int out_size, void* d_ws, size_t ws_size,
                              hipStream_t stream) {
    const float *x = nullptr, *wqkv = nullptr, *wout = nullptr, *bout = nullptr;
    for (int i = 0; i < n_in; ++i) {
        switch (in_sizes[i]) {
            case NBATCH * EMBED * SEQ:   x    = (const float*)d_in[i]; break;  // 6291456
            case 3 * EMBED * EMBED:      wqkv = (const float*)d_in[i]; break;  // 442368
            case EMBED * EMBED:          wout = (const float*)d_in[i]; break;  // 147456
            case EMBED:                  bout = (const float*)d_in[i]; break;  // 384
        }
    }
    float* out = (float*)d_out;

    bf16* ws = (bf16*)d_ws;
    const size_t NE = (size_t)NBATCH * SEQ * EMBED;  // 6.29M elems
    bf16* tok   = ws;
    bf16* q     = ws + NE;
    bf16* k     = ws + 2 * NE;
    bf16* vT    = ws + 3 * NE;
    bf16* ao    = ws + 4 * NE;
    bf16* wqkvb = ws + 5 * NE;
    bf16* woutb = wqkvb + 3 * EMBED * EMBED;

    const int nqkv = 3 * EMBED * EMBED;
    const int nout = EMBED * EMBED;
    k_cvt2<<<dim3((nqkv + nout) / 4 / 256), 256, 0, stream>>>(wqkv, wout, wqkvb, woutb,
                                                              nqkv, nout);

    k_transpose<<<dim3(16, 6, 16), 256, 0, stream>>>(x, tok);
    k_qkv<<<dim3(1152), 256, 0, stream>>>(tok, wqkvb, q, k, vT);
    k_attn<<<dim3(1536), 256, 0, stream>>>(q, k, vT, ao);
    k_proj<<<dim3(768), 256, 0, stream>>>(ao, woutb, bout, out);
}

// Round 9
// 170.052 us; speedup vs baseline: 1.3946x; 1.3946x over previous
//
#include <hip/hip_runtime.h>
#include <hip/hip_bf16.h>

#define EMBED 384
#define SEQ   1024
#define NBATCH 16
#define NH    6
#define HD    64

typedef __bf16 bf16;
typedef bf16  bf16x8 __attribute__((ext_vector_type(8)));
typedef bf16  bf16x4 __attribute__((ext_vector_type(4)));
typedef float f32x4  __attribute__((ext_vector_type(4)));

#define MFMA16(a, b, c) __builtin_amdgcn_mfma_f32_16x16x32_bf16((a), (b), (c), 0, 0, 0)

// q is pre-scaled by this in k_qkv so attention is P = exp2(S) directly
#define QSCALE 0.18033688011112042f  // 0.125 * log2(e)

// async global->LDS, 16B per lane; LDS dst = wave-uniform base + lane*16
__device__ __forceinline__ void gload_lds16(const void* g, void* l) {
    __builtin_amdgcn_global_load_lds(
        (const __attribute__((address_space(1))) void*)g,
        (__attribute__((address_space(3))) void*)l, 16, 0, 0);
}

// ---------------------------------------------------------------------------
// K-1: f32 -> bf16 conversion for both weight arrays, float4-vectorized
// ---------------------------------------------------------------------------
__global__ __launch_bounds__(256) void k_cvt2(const float* __restrict__ a,
                                              const float* __restrict__ b,
                                              bf16* __restrict__ da,
                                              bf16* __restrict__ db,
                                              int na, int nb) {
    int i = (blockIdx.x * 256 + threadIdx.x) * 4;
    if (i < na) {
        float4 v = *reinterpret_cast<const float4*>(a + i);
        bf16x4 o = {(bf16)v.x, (bf16)v.y, (bf16)v.z, (bf16)v.w};
        *reinterpret_cast<bf16x4*>(da + i) = o;
    } else {
        int j = i - na;
        if (j < nb) {
            float4 v = *reinterpret_cast<const float4*>(b + j);
            bf16x4 o = {(bf16)v.x, (bf16)v.y, (bf16)v.z, (bf16)v.w};
            *reinterpret_cast<bf16x4*>(db + j) = o;
        }
    }
}

// ---------------------------------------------------------------------------
// K0: x[n][c][s] (f32) -> tok[n][s][c] (bf16)  tile transpose through LDS
// ---------------------------------------------------------------------------
__global__ __launch_bounds__(256) void k_transpose(const float* __restrict__ x,
                                                   bf16* __restrict__ tok) {
    __shared__ bf16 tile[64][66];
    int n  = blockIdx.z;
    int s0 = blockIdx.x * 64;
    int c0 = blockIdx.y * 64;
    int tid = threadIdx.x;

    int sl  = tid & 63;
    int cl0 = tid >> 6;  // 0..3
#pragma unroll
    for (int i = 0; i < 16; ++i) {
        int cl = cl0 + i * 4;
        tile[cl][sl] = (bf16)x[((size_t)n * EMBED + (c0 + cl)) * SEQ + s0 + sl];
    }
    __syncthreads();
    int cl  = tid & 63;
    int sl0 = tid >> 6;
#pragma unroll
    for (int i = 0; i < 16; ++i) {
        int s = sl0 + i * 4;
        tok[((size_t)n * SEQ + (s0 + s)) * EMBED + c0 + cl] = tile[cl][s];
    }
}

// ---------------------------------------------------------------------------
// K1: qkv, double-buffered LDS staging (BK=32). Manual x2 unroll inside a
//   pinned-rolled loop: compile-time buffer index, bounded VGPR.
//   q written pre-scaled by QSCALE.
// ---------------------------------------------------------------------------
__global__ __launch_bounds__(256) void k_qkv(const bf16* __restrict__ tok,
                                             const bf16* __restrict__ wqkv,
                                             bf16* __restrict__ qout,
                                             bf16* __restrict__ kout,
                                             bf16* __restrict__ vtout) {
    __shared__ __align__(16) bf16 At[2][128 * 32];  // 8KB each, 64B rows
    __shared__ __align__(16) bf16 Bt[2][128 * 32];

    int b    = blockIdx.x;       // 1152 blocks
    int bm   = b & 7;            // 8 s-tiles -> XCD
    int g    = b >> 3;
    int bn   = g % 9;            // 9 o-tiles
    int n    = g / 9;
    int wave = threadIdx.x >> 6;
    int lane = threadIdx.x & 63;
    int row16 = lane & 15;
    int quad  = lane >> 4;
    int sw_base = (wave >> 1) * 64;   // wave row offset within tile
    int ow_base = (wave & 1) * 64;

    const bf16* Ag = tok  + ((size_t)n * SEQ + bm * 128) * EMBED;
    const bf16* Bg = wqkv + (size_t)bn * 128 * EMBED;

    int srow = lane >> 2;        // 0..15 within 16-row slab
    int scol = (lane & 3) * 8;   // 8 elems = 16B
    const bf16* Abase = Ag + (size_t)(wave * 32 + srow) * EMBED + scol;
    const bf16* Bbase = Bg + (size_t)(wave * 32 + srow) * EMBED + scol;
    bf16* AtW = &At[0][0] + wave * 32 * 32;   // uniform LDS slab base
    bf16* BtW = &Bt[0][0] + wave * 32 * 32;

    auto stage = [&](int kk, int bi) {
        gload_lds16(Abase + kk,               AtW + bi * 128 * 32);
        gload_lds16(Abase + kk + 16 * EMBED,  AtW + bi * 128 * 32 + 16 * 32);
        gload_lds16(Bbase + kk,               BtW + bi * 128 * 32);
        gload_lds16(Bbase + kk + 16 * EMBED,  BtW + bi * 128 * 32 + 16 * 32);
    };

    f32x4 acc[4][4] = {};
    auto gemmstep = [&](const bf16* at, const bf16* bt) {
        bf16x8 af[4], bfr[4];
#pragma unroll
        for (int mt = 0; mt < 4; ++mt)
            af[mt] = *reinterpret_cast<const bf16x8*>(
                at + (sw_base + mt * 16 + row16) * 32 + quad * 8);
#pragma unroll
        for (int nt = 0; nt < 4; ++nt)
            bfr[nt] = *reinterpret_cast<const bf16x8*>(
                bt + (ow_base + nt * 16 + row16) * 32 + quad * 8);
#pragma unroll
        for (int mt = 0; mt < 4; ++mt)
#pragma unroll
            for (int nt = 0; nt < 4; ++nt)
                acc[mt][nt] = MFMA16(af[mt], bfr[nt], acc[mt][nt]);
    };

    stage(0, 0);
#pragma unroll 1
    for (int s2 = 0; s2 < 6; ++s2) {
        int kk = s2 * 64;
        __syncthreads();
        stage(kk + 32, 1);               // step 2*s2+1 <= 11: always valid
        gemmstep(&At[0][0], &Bt[0][0]);
        __syncthreads();
        if (s2 < 5) stage(kk + 64, 0);
        gemmstep(&At[1][0], &Bt[1][0]);
    }

    int s_base = bm * 128 + sw_base;
    int o_base = bn * 128 + ow_base;
    int part = (bn * 128) / EMBED;  // o-tile never crosses a part boundary
#pragma unroll
    for (int mt = 0; mt < 4; ++mt)
#pragma unroll
        for (int nt = 0; nt < 4; ++nt) {
            int o   = o_base + nt * 16 + row16;
            int rem = o - part * EMBED;
            int h = rem >> 6;
            int d = rem & 63;
            if (part == 0) {        // q: pre-scale by 0.125*log2(e)
#pragma unroll
                for (int r = 0; r < 4; ++r) {
                    int s = s_base + mt * 16 + quad * 4 + r;
                    qout[(((size_t)n * NH + h) * SEQ + s) * HD + d] =
                        (bf16)(acc[mt][nt][r] * QSCALE);
                }
            } else if (part == 1) { // k
#pragma unroll
                for (int r = 0; r < 4; ++r) {
                    int s = s_base + mt * 16 + quad * 4 + r;
                    kout[(((size_t)n * NH + h) * SEQ + s) * HD + d] = (bf16)acc[mt][nt][r];
                }
            } else {                // vT: 4 consecutive s -> 8B store
                int s = s_base + mt * 16 + quad * 4;
                bf16x4 pack;
#pragma unroll
                for (int r = 0; r < 4; ++r) pack[r] = (bf16)acc[mt][nt][r];
                *reinterpret_cast<bf16x4*>(
                    &vtout[(((size_t)n * NH + h) * HD + d) * SEQ + s]) = pack;
            }
        }
}

// ---------------------------------------------------------------------------
// K2: attention v6 = R7 rolled structure (VGPR ~70, occupancy ~25%) +
//   QSCALE fold (P = exp2(S)) + hoisted staging bases. Manual x2 unroll in a
//   pinned-rolled loop gives compile-time LDS buffer bases WITHOUT the R8
//   register blowup (full unroll -> VGPR 152 -> occupancy 11% -> 2x FETCH).
// ---------------------------------------------------------------------------
__global__ __launch_bounds__(256) void k_attn(const bf16* __restrict__ q,
                                              const bf16* __restrict__ kmat,
                                              const bf16* __restrict__ vT,
                                              bf16* __restrict__ ao) {
    __shared__ __align__(16) bf16 ktile[2][64 * 64];   // swizzled [t][d]
    __shared__ __align__(16) bf16 vtile[2][64 * 64];   // swizzled [d][t]
    __shared__ __align__(16) bf16 pshare[4][16][72];   // wave-private P tile

    int b     = blockIdx.x;      // 1536 blocks
    int lane8 = b & 7;           // -> XCD (round-robin heuristic)
    int g     = b >> 3;
    int nh    = (g % 12) * 8 + lane8;   // all qt of one nh share lane8
    int qt    = g / 12;
    int n = nh / NH, h = nh % NH;

    int wave = threadIdx.x >> 6;
    int lane = threadIdx.x & 63;
    int row16 = lane & 15;
    int quad  = lane >> 4;
    int sw    = row16 & 7;       // read-side swizzle key
    int s_row = qt * 64 + wave * 16;

    const bf16* qh = q    + ((size_t)n * NH + h) * SEQ * HD;
    const bf16* kh = kmat + ((size_t)n * NH + h) * SEQ * HD;
    const bf16* vh = vT   + ((size_t)n * NH + h) * HD * SEQ;

    bf16x8 qf0 = *reinterpret_cast<const bf16x8*>(qh + (size_t)(s_row + row16) * HD + quad * 8);
    bf16x8 qf1 = *reinterpret_cast<const bf16x8*>(qh + (size_t)(s_row + row16) * HD + 32 + quad * 8);

    // hoisted per-lane staging sources. Slab j=+8 keeps (row&7) -> same ck.
    int r0   = wave * 16;
    int srow = r0 + (lane >> 3);           // tile row this lane feeds (j=0 slab)
    int ck   = (lane & 7) ^ (srow & 7);    // swizzled source chunk (j-invariant)
    const bf16* kbase = kh + (size_t)srow * HD + ck * 8;   // +t0*HD per iter
    const bf16* vbase = vh + (size_t)srow * SEQ + ck * 8;  // +t0 per iter
    bf16* ktW = &ktile[0][0] + r0 * 64;    // uniform LDS slab bases
    bf16* vtW = &vtile[0][0] + r0 * 64;

    auto stage = [&](int t0, int bi) {
        int lb = bi * 64 * 64;
        gload_lds16(kbase + (size_t)t0 * HD,           ktW + lb);
        gload_lds16(kbase + (size_t)t0 * HD + 8 * HD,  ktW + lb + 8 * 64);
        gload_lds16(vbase + t0,                        vtW + lb);
        gload_lds16(vbase + t0 + 8 * SEQ,              vtW + lb + 8 * 64);
    };

    float lsum[4] = {0.f, 0.f, 0.f, 0.f};
    f32x4 oacc[4] = {};

    auto body = [&](const bf16* kb, const bf16* vb) {
        // S^T = K*Q'^T: lane holds S[m=row16][t=nt*16+quad*4+r]
        f32x4 sacc[4] = {};
#pragma unroll
        for (int nt = 0; nt < 4; ++nt) {
            bf16x8 kf0 = *reinterpret_cast<const bf16x8*>(
                kb + (nt * 16 + row16) * 64 + ((quad ^ sw) * 8));
            bf16x8 kf1 = *reinterpret_cast<const bf16x8*>(
                kb + (nt * 16 + row16) * 64 + (((4 + quad) ^ sw) * 8));
            sacc[nt] = MFMA16(kf0, qf0, sacc[nt]);
            sacc[nt] = MFMA16(kf1, qf1, sacc[nt]);
        }
        // P = exp2(S); packed 8B LDS writes
#pragma unroll
        for (int nt = 0; nt < 4; ++nt) {
            bf16x4 pk;
            float ps = 0.f;
#pragma unroll
            for (int r = 0; r < 4; ++r) {
                float e = __builtin_amdgcn_exp2f(sacc[nt][r]);
                ps += e;
                pk[r] = (bf16)e;
            }
            lsum[nt] += ps;
            *reinterpret_cast<bf16x4*>(&pshare[wave][row16][nt * 16 + quad * 4]) = pk;
        }
        __builtin_amdgcn_wave_barrier();  // wave-private LDS write -> read order
        bf16x8 pf0 = *reinterpret_cast<const bf16x8*>(&pshare[wave][row16][quad * 8]);
        bf16x8 pf1 = *reinterpret_cast<const bf16x8*>(&pshare[wave][row16][32 + quad * 8]);
        __builtin_amdgcn_wave_barrier();  // read -> next iter's writes
        // O += P*V
#pragma unroll
        for (int dt = 0; dt < 4; ++dt) {
            bf16x8 vf0 = *reinterpret_cast<const bf16x8*>(
                vb + (dt * 16 + row16) * 64 + ((quad ^ sw) * 8));
            bf16x8 vf1 = *reinterpret_cast<const bf16x8*>(
                vb + (dt * 16 + row16) * 64 + (((4 + quad) ^ sw) * 8));
            oacc[dt] = MFMA16(pf0, vf0, oacc[dt]);
            oacc[dt] = MFMA16(pf1, vf1, oacc[dt]);
        }
    };

    stage(0, 0);
#pragma unroll 1
    for (int it2 = 0; it2 < 8; ++it2) {
        int t0 = it2 * 128;
        __syncthreads();
        stage(t0 + 64, 1);               // tile 2*it2+1 <= 15: always valid
        body(&ktile[0][0], &vtile[0][0]);
        __syncthreads();
        if (it2 < 7) stage(t0 + 128, 0);
        body(&ktile[1][0], &vtile[1][0]);
    }

    // row-sum: lane's lsum covers t ≡ {4*quad..4*quad+3} mod 16 for row=row16
    float tot = (lsum[0] + lsum[1]) + (lsum[2] + lsum[3]);
    tot += __shfl_xor(tot, 16, 64);
    tot += __shfl_xor(tot, 32, 64);
    float inv = 1.0f / tot;  // valid for row = lane&15

    float linv[4];
#pragma unroll
    for (int r = 0; r < 4; ++r) linv[r] = __shfl(inv, quad * 4 + r, 64);

#pragma unroll
    for (int dt = 0; dt < 4; ++dt)
#pragma unroll
        for (int r = 0; r < 4; ++r) {
            int s = s_row + quad * 4 + r;
            int d = dt * 16 + row16;
            ao[((size_t)n * SEQ + s) * EMBED + h * HD + d] = (bf16)(oacc[dt][r] * linv[r]);
        }
}

// ---------------------------------------------------------------------------
// K3: out[n][o][s] = bias[o] + sum_c ao[n][s][c] * wout[o][c]   (f32 output)
//   64(s) x 128(o) block tile, now with double-buffered LDS staging (BK=32).
// ---------------------------------------------------------------------------
__global__ __launch_bounds__(256) void k_proj(const bf16* __restrict__ ao,
                                              const bf16* __restrict__ wout,
                                              const float* __restrict__ bout,
                                              float* __restrict__ out) {
    __shared__ __align__(16) bf16 At[2][64 * 32];    // 4KB each
    __shared__ __align__(16) bf16 Bt[2][128 * 32];   // 8KB each

    int b    = blockIdx.x;       // 768 blocks
    int bm   = b & 15;           // 16 s-tiles of 64
    int g    = b >> 4;
    int bn   = g % 3;            // 3 o-tiles
    int n    = g / 3;
    int wave = threadIdx.x >> 6;
    int lane = threadIdx.x & 63;
    int row16 = lane & 15;
    int quad  = lane >> 4;
    int sw_base = (wave >> 1) * 32;
    int ow_base = (wave & 1) * 64;

    const bf16* Ag = ao + ((size_t)n * SEQ + bm * 64) * EMBED;

    int srow = lane >> 2;        // 0..15
    int scol = (lane & 3) * 8;
    const bf16* Abase = Ag   + (size_t)(wave * 16 + srow) * EMBED + scol;
    const bf16* Bbase = wout + (size_t)(bn * 128 + wave * 32 + srow) * EMBED + scol;
    bf16* AtW = &At[0][0] + wave * 16 * 32;
    bf16* BtW = &Bt[0][0] + wave * 32 * 32;

    auto stage = [&](int kk, int bi) {
        gload_lds16(Abase + kk,               AtW + bi * 64 * 32);
        gload_lds16(Bbase + kk,               BtW + bi * 128 * 32);
        gload_lds16(Bbase + kk + 16 * EMBED,  BtW + bi * 128 * 32 + 16 * 32);
    };

    f32x4 acc[2][4] = {};
    auto gemmstep = [&](const bf16* at, const bf16* bt) {
        bf16x8 af[2], bfr[4];
#pragma unroll
        for (int mt = 0; mt < 2; ++mt)
            af[mt] = *reinterpret_cast<const bf16x8*>(
                at + (sw_base + mt * 16 + row16) * 32 + quad * 8);
#pragma unroll
        for (int nt = 0; nt < 4; ++nt)
            bfr[nt] = *reinterpret_cast<const bf16x8*>(
                bt + (ow_base + nt * 16 + row16) * 32 + quad * 8);
#pragma unroll
        for (int mt = 0; mt < 2; ++mt)
#pragma unroll
            for (int nt = 0; nt < 4; ++nt)
                acc[mt][nt] = MFMA16(af[mt], bfr[nt], acc[mt][nt]);
    };

    stage(0, 0);
#pragma unroll 1
    for (int s2 = 0; s2 < 6; ++s2) {
        int kk = s2 * 64;
        __syncthreads();
        stage(kk + 32, 1);
        gemmstep(&At[0][0], &Bt[0][0]);
        __syncthreads();
        if (s2 < 5) stage(kk + 64, 0);
        gemmstep(&At[1][0], &Bt[1][0]);
    }

    int s_base = bm * 64 + sw_base;
    int o_base = bn * 128 + ow_base;
#pragma unroll
    for (int nt = 0; nt < 4; ++nt) {
        int o = o_base + nt * 16 + row16;
        float bias = bout[o];
#pragma unroll
        for (int mt = 0; mt < 2; ++mt) {
            int s = s_base + mt * 16 + quad * 4;  // 4 consecutive s, 16B store
            f32x4 pack;
#pragma unroll
            for (int r = 0; r < 4; ++r) pack[r] = acc[mt][nt][r] + bias;
            *reinterpret_cast<f32x4*>(out + ((size_t)n * EMBED + o) * SEQ + s) = pack;
        }
    }
}

// ---------------------------------------------------------------------------
extern "C" void kernel_launch(void* const* d_in, const int* in_sizes, int n_in,
                              void* d_out, int out_size, void* d_ws, size_t ws_size,
                              hipStream_t stream) {
    const float *x = nullptr, *wqkv = nullptr, *wout = nullptr, *bout = nullptr;
    for (int i = 0; i < n_in; ++i) {
        switch (in_sizes[i]) {
            case NBATCH * EMBED * SEQ:   x    = (const float*)d_in[i]; break;  // 6291456
            case 3 * EMBED * EMBED:      wqkv = (const float*)d_in[i]; break;  // 442368
            case EMBED * EMBED:          wout = (const float*)d_in[i]; break;  // 147456
            case EMBED:                  bout = (const float*)d_in[i]; break;  // 384
        }
    }
    float* out = (float*)d_out;

    bf16* ws = (bf16*)d_ws;
    const size_t NE = (size_t)NBATCH * SEQ * EMBED;  // 6.29M elems
    bf16* tok   = ws;
    bf16* q     = ws + NE;
    bf16* k     = ws + 2 * NE;
    bf16* vT    = ws + 3 * NE;
    bf16* ao    = ws + 4 * NE;
    bf16* wqkvb = ws + 5 * NE;
    bf16* woutb = wqkvb + 3 * EMBED * EMBED;

    const int nqkv = 3 * EMBED * EMBED;
    const int nout = EMBED * EMBED;
    k_cvt2<<<dim3((nqkv + nout) / 4 / 256), 256, 0, stream>>>(wqkv, wout, wqkvb, woutb,
                                                              nqkv, nout);

    k_transpose<<<dim3(16, 6, 16), 256, 0, stream>>>(x, tok);
    k_qkv<<<dim3(1152), 256, 0, stream>>>(tok, wqkvb, q, k, vT);
    k_attn<<<dim3(1536), 256, 0, stream>>>(q, k, vT, ao);
    k_proj<<<dim3(768), 256, 0, stream>>>(ao, woutb, bout, out);
}